// Round 1
// baseline (931.234 us; speedup 1.0000x reference)
//
#include <hip/hip_runtime.h>
#include <math.h>

// Problem constants
#define NW        4096   // words
#define WLEN      16     // chars per word
#define CEMB      50
#define CHID      128
#define NGATE     512    // 4*CHID
#define GDIM      300
#define FEAT      428    // GDIM + CHID
#define NHID      512
#define CVOCAB    100

// ws layout (floats):
//   [0, 428)           feature sums (divide by 4096 in head kernel)
//   [512, 512+100*512) P table = char_embed @ W_ih.T + b_ih + b_hh

// ---------------------------------------------------------------- glove mean
__global__ void glove_sum_kernel(const int* __restrict__ word_idx,
                                 const float* __restrict__ glove,
                                 float* __restrict__ sums) {
    const int tid = threadIdx.x;           // 256 threads
    const int wbase = blockIdx.x * 16;     // 256 blocks * 16 words
    float acc0 = 0.f, acc1 = 0.f;
    for (int w = 0; w < 16; ++w) {
        const int row = word_idx[wbase + w];
        const float* r = glove + (size_t)row * GDIM;
        if (tid < GDIM) acc0 += r[tid];
        if (tid + 256 < GDIM) acc1 += r[tid + 256];
    }
    if (tid < GDIM) atomicAdd(&sums[tid], acc0);
    if (tid + 256 < GDIM) atomicAdd(&sums[tid + 256], acc1);
}

// ------------------------------------------------- input-projection table P
// P[c][j] = sum_e char_embed[c][e] * W_ih[j][e] + b_ih[j] + b_hh[j]
__global__ void inproj_kernel(const float* __restrict__ char_embed, // [100][50]
                              const float* __restrict__ W_ih,       // [512][50]
                              const float* __restrict__ b_ih,
                              const float* __restrict__ b_hh,
                              float* __restrict__ P) {              // [100][512]
    const int j = threadIdx.x;  // 512 threads, 1 block
    float w[CEMB];
#pragma unroll
    for (int e = 0; e < CEMB; ++e) w[e] = W_ih[j * CEMB + e];
    const float b = b_ih[j] + b_hh[j];
    __shared__ float ce[CEMB];
    for (int c = 0; c < CVOCAB; ++c) {
        __syncthreads();
        if (j < CEMB) ce[j] = char_embed[c * CEMB + j];
        __syncthreads();
        float acc = b;
#pragma unroll
        for (int e = 0; e < CEMB; ++e) acc = fmaf(ce[e], w[e], acc);
        P[c * NGATE + j] = acc;
    }
}

// ----------------------------------------------------------------- the LSTM
// 256 blocks x 512 threads; each block owns 16 words for all 16 timesteps.
// Thread t owns gate row j=t: W_hh row in 128 VGPRs; h in LDS (broadcast reads).
__global__ __launch_bounds__(512, 2)
void lstm_kernel(const int* __restrict__ char_idx,  // [4096][16]
                 const float* __restrict__ Whh,     // [512][128]
                 const float* __restrict__ P,       // [100][512]
                 float* __restrict__ sums) {
    __shared__ float h[16][CHID];       // 8 KB
    __shared__ float gates[16][NGATE];  // 32 KB
    __shared__ int   ci[16][WLEN];      // 1 KB
    const int t = threadIdx.x;          // gate row j = t

    // Preload W_hh row into registers (32 float4 = 128 VGPRs)
    float4 wr[32];
    const float4* wrow = (const float4*)(Whh + (size_t)t * CHID);
#pragma unroll
    for (int kc = 0; kc < 32; ++kc) wr[kc] = wrow[kc];

    // Preload this block's char indices
    const int wbase = blockIdx.x * 16;
    if (t < 256) ci[t >> 4][t & 15] = char_idx[(wbase + (t >> 4)) * WLEN + (t & 15)];

    // Zero h
#pragma unroll
    for (int r = 0; r < 4; ++r) {
        const int idx = t + r * 512;
        h[idx >> 7][idx & 127] = 0.f;
    }

    // Cell-state registers: thread owns cells (w, n) for w = q + 4r
    const int n = t & 127, q = t >> 7;
    float cc[4] = {0.f, 0.f, 0.f, 0.f};

    __syncthreads();

    for (int step = 0; step < WLEN; ++step) {
        float acc[16];
#pragma unroll
        for (int w = 0; w < 16; ++w) acc[w] = P[ci[w][step] * NGATE + t];

#pragma unroll
        for (int kc = 0; kc < 32; ++kc) {
#pragma unroll
            for (int w = 0; w < 16; ++w) {
                const float4 h4 = *(const float4*)&h[w][kc * 4];
                acc[w] = fmaf(wr[kc].x, h4.x, acc[w]);
                acc[w] = fmaf(wr[kc].y, h4.y, acc[w]);
                acc[w] = fmaf(wr[kc].z, h4.z, acc[w]);
                acc[w] = fmaf(wr[kc].w, h4.w, acc[w]);
            }
        }
#pragma unroll
        for (int w = 0; w < 16; ++w) gates[w][t] = acc[w];
        __syncthreads();

        // Cell update: 4 cells per thread
#pragma unroll
        for (int r = 0; r < 4; ++r) {
            const int w = q + 4 * r;
            const float ig = gates[w][n];
            const float fg = gates[w][128 + n];
            const float gg = gates[w][256 + n];
            const float og = gates[w][384 + n];
            const float si = 1.f / (1.f + expf(-ig));
            const float sf = 1.f / (1.f + expf(-fg));
            const float so = 1.f / (1.f + expf(-og));
            cc[r] = sf * cc[r] + si * tanhf(gg);
            h[w][n] = so * tanhf(cc[r]);
        }
        __syncthreads();
    }

    // Sum h over this block's 16 words -> atomic into char part of sums
    if (t < CHID) {
        float s = 0.f;
#pragma unroll
        for (int w = 0; w < 16; ++w) s += h[w][t];
        atomicAdd(&sums[GDIM + t], s);
    }
}

// ------------------------------------------------------------------- head
__global__ void head_kernel(const float* __restrict__ fc1_w, // [512][428]
                            const float* __restrict__ fc1_b,
                            const float* __restrict__ fc2_w, // [2][512]
                            const float* __restrict__ fc2_b,
                            const float* __restrict__ sums,
                            float* __restrict__ out) {
    __shared__ float avg[FEAT];
    __shared__ float hid[NHID];
    const int t = threadIdx.x;  // 512 threads, 1 block
    if (t < FEAT) avg[t] = sums[t] * (1.f / (float)NW);
    __syncthreads();

    float acc = fc1_b[t];
    const float4* row4 = (const float4*)(fc1_w + (size_t)t * FEAT);
#pragma unroll 4
    for (int i = 0; i < FEAT / 4; ++i) {
        const float4 wv = row4[i];
        acc = fmaf(avg[4 * i + 0], wv.x, acc);
        acc = fmaf(avg[4 * i + 1], wv.y, acc);
        acc = fmaf(avg[4 * i + 2], wv.z, acc);
        acc = fmaf(avg[4 * i + 3], wv.w, acc);
    }
    hid[t] = fmaxf(acc, 0.f);
    __syncthreads();

    const int wave = t >> 6, lane = t & 63;
    if (wave < 2) {
        float p = 0.f;
        for (int j = lane; j < NHID; j += 64)
            p = fmaf(hid[j], fc2_w[wave * NHID + j], p);
#pragma unroll
        for (int off = 32; off > 0; off >>= 1) p += __shfl_down(p, off);
        if (lane == 0) out[wave] = p + fc2_b[wave];
    }
}

// ---------------------------------------------------------------- launcher
extern "C" void kernel_launch(void* const* d_in, const int* in_sizes, int n_in,
                              void* d_out, int out_size, void* d_ws, size_t ws_size,
                              hipStream_t stream) {
    const int*   word_idx   = (const int*)d_in[0];
    const int*   char_idx   = (const int*)d_in[1];
    const float* glove      = (const float*)d_in[2];
    const float* char_embed = (const float*)d_in[3];
    const float* W_ih       = (const float*)d_in[4];
    const float* W_hh       = (const float*)d_in[5];
    const float* b_ih       = (const float*)d_in[6];
    const float* b_hh       = (const float*)d_in[7];
    const float* fc1_w      = (const float*)d_in[8];
    const float* fc1_b      = (const float*)d_in[9];
    const float* fc2_w      = (const float*)d_in[10];
    const float* fc2_b      = (const float*)d_in[11];
    float* out = (float*)d_out;
    float* ws  = (float*)d_ws;

    float* sums = ws;        // 428 floats
    float* P    = ws + 512;  // 100*512 floats

    hipMemsetAsync(sums, 0, FEAT * sizeof(float), stream);
    glove_sum_kernel<<<256, 256, 0, stream>>>(word_idx, glove, sums);
    inproj_kernel<<<1, 512, 0, stream>>>(char_embed, W_ih, b_ih, b_hh, P);
    lstm_kernel<<<256, 512, 0, stream>>>(char_idx, W_hh, P, sums);
    head_kernel<<<1, 512, 0, stream>>>(fc1_w, fc1_b, fc2_w, fc2_b, sums, out);
}

// Round 5
// 616.380 us; speedup vs baseline: 1.5108x; 1.5108x over previous
//
#include <hip/hip_runtime.h>
#include <hip/hip_bf16.h>
#include <math.h>

// Problem constants
#define NW        4096   // words
#define WLEN      16     // chars per word
#define CEMB      50
#define CHID      128
#define NGATE     512    // 4*CHID
#define GDIM      300
#define FEAT      428    // GDIM + CHID
#define NHID      512
#define CVOCAB    100
#define NBLK      256    // blocks for glove/lstm

// ws layout (floats) — all regions fully written every launch:
//   [0, 428)                      sums (written by reduce_kernel)
//   [512, 512+51200)              P table = char_embed @ W_ih.T + b_ih + b_hh
//   [51712, 52224)                relu(fc1) hidden (512)
//   [52224, 52224+256*304)        gpart: per-block glove partials [b][304]
//   [130048, 130048+256*128)      cpart: per-block char-h partials [b][128]

typedef __attribute__((ext_vector_type(8))) short bf16x8;
typedef __attribute__((ext_vector_type(4))) float f32x4;

__device__ __forceinline__ unsigned short f2bf(float x) {
    __hip_bfloat16 h = __float2bfloat16(x);   // RNE
    return __builtin_bit_cast(unsigned short, h);
}
__device__ __forceinline__ float bf2f(unsigned short u) {
    unsigned int v = ((unsigned int)u) << 16;
    return __builtin_bit_cast(float, v);
}
__device__ __forceinline__ float sigmoid_f(float x) { return 1.f / (1.f + expf(-x)); }

// ---------------------------------------------------------------- glove part
// 256 blocks x 256 threads; block b sums its 16 words' glove rows -> gpart[b][*]
__global__ void glove_sum_kernel(const int* __restrict__ word_idx,
                                 const float* __restrict__ glove,
                                 float* __restrict__ gpart) {
    const int tid = threadIdx.x;
    const int b = blockIdx.x;
    const int wbase = b * 16;
    float acc0 = 0.f, acc1 = 0.f;
#pragma unroll
    for (int w = 0; w < 16; ++w) {
        const int row = word_idx[wbase + w];
        const float* r = glove + (size_t)row * GDIM;
        if (tid < GDIM) acc0 += r[tid];
        if (tid + 256 < GDIM) acc1 += r[tid + 256];
    }
    if (tid < GDIM) gpart[b * 304 + tid] = acc0;
    if (tid + 256 < GDIM) gpart[b * 304 + tid + 256] = acc1;
}

// ------------------------------------------------- input-projection table P
// grid 400 = 100 chars x 4 gate-tiles of 128; 128 threads. All fp32.
__global__ void inproj_kernel(const float* __restrict__ char_embed, // [100][50]
                              const float* __restrict__ W_ih,       // [512][50]
                              const float* __restrict__ b_ih,
                              const float* __restrict__ b_hh,
                              float* __restrict__ P) {              // [100][512]
    __shared__ float slab[128 * 51];  // padded stride 51 -> conflict-free
    __shared__ float ce[CEMB];
    const int c = blockIdx.x >> 2, jt = blockIdx.x & 3;
    const int t = threadIdx.x;  // 128
    for (int s = t; s < 128 * CEMB; s += 128) {
        const int j = s / CEMB, e = s - j * CEMB;
        slab[j * 51 + e] = W_ih[jt * (128 * CEMB) + s];
    }
    if (t < CEMB) ce[t] = char_embed[c * CEMB + t];
    __syncthreads();
    const int g = jt * 128 + t;
    float acc = b_ih[g] + b_hh[g];
#pragma unroll
    for (int e = 0; e < CEMB; ++e) acc = fmaf(ce[e], slab[t * 51 + e], acc);
    P[c * NGATE + g] = acc;
}

// ----------------------------------------------------------------- the LSTM
// 256 blocks x 512 threads (8 waves); block owns 16 words, 16 steps.
// Split-precision MFMA: Whh = Ahi + Alo (bf16 pair), H = Bhi + Blo (bf16 pair).
// G = Ahi*Bhi + Alo*Bhi + Ahi*Blo  (fp32 accum; dropped term ~2^-18 relative).
// Wave wm owns m-tiles {wm, wm+8, wm+16, wm+24} = i/f/g/o gates of cells
// [wm*16, wm*16+16) -> all four gates of a cell land in the same thread.
// Final per-block h-sums go to cpart[b][128] (NO atomics -> bit-deterministic).
__global__ __launch_bounds__(512, 2)
void lstm_kernel(const int* __restrict__ char_idx,  // [4096][16]
                 const float* __restrict__ Whh,     // [512][128]
                 const float* __restrict__ P,       // [100][512]
                 float* __restrict__ cpart) {       // [256][128]
    __shared__ __align__(16) unsigned short Hh[16 * 128];  // hi part, swizzled, 4KB
    __shared__ __align__(16) unsigned short Hl[16 * 128];  // lo part, swizzled, 4KB
    __shared__ int ci[16][17];                             // [word][step], padded
    const int t = threadIdx.x;
    const int wm = t >> 6, lane = t & 63;
    const int w = lane & 15, hi = lane >> 4;

    // ---- A fragments: Whh split hi/lo bf16. m = lane&15; k = ks*32 + hi*8 + j
    // (A and B use the same positional lane->k map, so contraction is exact).
    bf16x8 ah[4][4], al[4][4];
#pragma unroll
    for (int r = 0; r < 4; ++r) {
        const int g = (wm + 8 * r) * 16 + (lane & 15);
        const float* wp = Whh + g * CHID + hi * 8;
#pragma unroll
        for (int ks = 0; ks < 4; ++ks) {
            union { bf16x8 v; unsigned short u[8]; } ph, pl;
#pragma unroll
            for (int j = 0; j < 8; ++j) {
                const float x = wp[ks * 32 + j];
                const unsigned short xh = f2bf(x);
                ph.u[j] = xh;
                pl.u[j] = f2bf(x - bf2f(xh));
            }
            ah[r][ks] = ph.v;
            al[r][ks] = pl.v;
        }
    }

    // ---- char indices for this block's 16 words
    const int wbase = blockIdx.x * 16;
    if (t < 256) ci[t >> 4][t & 15] = char_idx[(wbase + (t >> 4)) * WLEN + (t & 15)];

    // ---- zero H (bf16 zero == 0 bits)
    {
        unsigned int* hz = (unsigned int*)Hh;
        hz[t] = 0u; hz[t + 512] = 0u;
        unsigned int* lz = (unsigned int*)Hl;
        lz[t] = 0u; lz[t + 512] = 0u;
    }

    float cst[4] = {0.f, 0.f, 0.f, 0.f};
    float hreg[4] = {0.f, 0.f, 0.f, 0.f};
    __syncthreads();

    for (int s = 0; s < WLEN; ++s) {
        // P gather for this step (issued early; consumed after MFMAs)
        const int cix = ci[w][s];
        const float* prow = P + cix * NGATE + wm * 16 + hi * 4;
        f32x4 pv[4];
#pragma unroll
        for (int r = 0; r < 4; ++r) pv[r] = *(const f32x4*)(prow + r * 128);

        // B fragments from swizzled LDS: b[ks][j] = H[ks*32+hi*8+j][w]
        bf16x8 bh[4], bl[4];
#pragma unroll
        for (int ks = 0; ks < 4; ++ks) {
            const int chunk = (ks * 4 + hi) ^ w;  // 16B-chunk XOR swizzle
            bh[ks] = *(const bf16x8*)((const char*)Hh + w * 256 + chunk * 16);
            bl[ks] = *(const bf16x8*)((const char*)Hl + w * 256 + chunk * 16);
        }

        // MFMA: d[r] = Ahi*Bhi + Alo*Bhi + Ahi*Blo (fp32 accum from zero)
        f32x4 d[4];
#pragma unroll
        for (int r = 0; r < 4; ++r) d[r] = (f32x4){0.f, 0.f, 0.f, 0.f};
#pragma unroll
        for (int ks = 0; ks < 4; ++ks)
#pragma unroll
            for (int r = 0; r < 4; ++r)
                d[r] = __builtin_amdgcn_mfma_f32_16x16x32_bf16(ah[r][ks], bh[ks], d[r], 0, 0, 0);
#pragma unroll
        for (int ks = 0; ks < 4; ++ks)
#pragma unroll
            for (int r = 0; r < 4; ++r)
                d[r] = __builtin_amdgcn_mfma_f32_16x16x32_bf16(al[r][ks], bh[ks], d[r], 0, 0, 0);
#pragma unroll
        for (int ks = 0; ks < 4; ++ks)
#pragma unroll
            for (int r = 0; r < 4; ++r)
                d[r] = __builtin_amdgcn_mfma_f32_16x16x32_bf16(ah[r][ks], bl[ks], d[r], 0, 0, 0);
        __syncthreads();  // all H reads done before overwrite

        // Cell update: thread owns cells n = wm*16 + hi*4 + reg, word w.
        // D layout (verified m89): col = lane&15 (= word), row = hi*4 + reg.
#pragma unroll
        for (int reg = 0; reg < 4; ++reg) {
            const float ig = d[0][reg] + pv[0][reg];
            const float fg = d[1][reg] + pv[1][reg];
            const float gg = d[2][reg] + pv[2][reg];
            const float og = d[3][reg] + pv[3][reg];
            const float si = sigmoid_f(ig);
            const float sf = sigmoid_f(fg);
            const float so = sigmoid_f(og);
            cst[reg] = sf * cst[reg] + si * tanhf(gg);   // libm tanh: no cancellation
            const float hv = so * tanhf(cst[reg]);
            hreg[reg] = hv;
            const int n = wm * 16 + hi * 4 + reg;
            const int idx = w * 128 + (((n >> 3) ^ w) << 3) + (n & 7);
            const unsigned short hh16 = f2bf(hv);
            Hh[idx] = hh16;
            Hl[idx] = f2bf(hv - bf2f(hh16));
        }
        __syncthreads();  // writes visible before next step's reads
    }

    // ---- reduce h over this block's 16 words (xor within 16-lane group),
    //      store per-block partial (deterministic, no atomics)
#pragma unroll
    for (int reg = 0; reg < 4; ++reg) {
        float v = hreg[reg];
#pragma unroll
        for (int m = 1; m < 16; m <<= 1) v += __shfl_xor(v, m);
        if ((lane & 15) == 0)
            cpart[blockIdx.x * CHID + wm * 16 + hi * 4 + reg] = v;
    }
}

// ------------------------------------------- deterministic partial reduction
// 1 block x 512 threads; thread t owns feature t; fixed serial order over b.
__global__ void reduce_kernel(const float* __restrict__ gpart, // [256][304]
                              const float* __restrict__ cpart, // [256][128]
                              float* __restrict__ sums) {      // [428]
    const int t = threadIdx.x;
    if (t >= FEAT) return;
    float a0 = 0.f, a1 = 0.f, a2 = 0.f, a3 = 0.f;
    if (t < GDIM) {
        for (int b = 0; b < NBLK; b += 4) {   // coalesced across t per iteration
            a0 += gpart[(b + 0) * 304 + t];
            a1 += gpart[(b + 1) * 304 + t];
            a2 += gpart[(b + 2) * 304 + t];
            a3 += gpart[(b + 3) * 304 + t];
        }
    } else {
        const int n = t - GDIM;
        for (int b = 0; b < NBLK; b += 4) {
            a0 += cpart[(b + 0) * CHID + n];
            a1 += cpart[(b + 1) * CHID + n];
            a2 += cpart[(b + 2) * CHID + n];
            a3 += cpart[(b + 3) * CHID + n];
        }
    }
    sums[t] = (a0 + a1) + (a2 + a3);
}

// ---------------------------------------------------------------- fc1 (relu)
// 32 blocks x 512 threads; block computes 16 rows; 32 lanes per row.
__global__ void fc1_kernel(const float* __restrict__ fc1_w, // [512][428]
                           const float* __restrict__ fc1_b,
                           const float* __restrict__ sums,
                           float* __restrict__ hid) {
    __shared__ __align__(16) float avg[FEAT];
    const int t = threadIdx.x;
    if (t < FEAT) avg[t] = sums[t] * (1.f / (float)NW);
    __syncthreads();

    const int wave = t >> 6, lane = t & 63;
    const int half = lane >> 5, lane32 = lane & 31;
    const int r = blockIdx.x * 16 + wave * 2 + half;

    float acc = 0.f;
    const float* row = fc1_w + (size_t)r * FEAT;
#pragma unroll
    for (int i = 0; i < 4; ++i) {
        const int c0 = i * 128 + lane32 * 4;
        if (c0 + 4 <= FEAT) {
            const f32x4 wv = *(const f32x4*)(row + c0);
            const f32x4 av = *(const f32x4*)(avg + c0);
            acc = fmaf(av[0], wv[0], acc);
            acc = fmaf(av[1], wv[1], acc);
            acc = fmaf(av[2], wv[2], acc);
            acc = fmaf(av[3], wv[3], acc);
        }
    }
#pragma unroll
    for (int m = 1; m < 32; m <<= 1) acc += __shfl_xor(acc, m);
    if (lane32 == 0) hid[r] = fmaxf(acc + fc1_b[r], 0.f);
}

// ---------------------------------------------------------------- fc2
__global__ void fc2_kernel(const float* __restrict__ fc2_w, // [2][512]
                           const float* __restrict__ fc2_b,
                           const float* __restrict__ hid,
                           float* __restrict__ out) {
    const int t = threadIdx.x;  // 128
    const int r = t >> 6, lane = t & 63;
    float p = 0.f;
#pragma unroll
    for (int i = 0; i < 8; ++i)
        p = fmaf(hid[i * 64 + lane], fc2_w[r * NHID + i * 64 + lane], p);
#pragma unroll
    for (int off = 32; off > 0; off >>= 1) p += __shfl_down(p, off);
    if (lane == 0) out[r] = p + fc2_b[r];
}

// ---------------------------------------------------------------- launcher
extern "C" void kernel_launch(void* const* d_in, const int* in_sizes, int n_in,
                              void* d_out, int out_size, void* d_ws, size_t ws_size,
                              hipStream_t stream) {
    const int*   word_idx   = (const int*)d_in[0];
    const int*   char_idx   = (const int*)d_in[1];
    const float* glove      = (const float*)d_in[2];
    const float* char_embed = (const float*)d_in[3];
    const float* W_ih       = (const float*)d_in[4];
    const float* W_hh       = (const float*)d_in[5];
    const float* b_ih       = (const float*)d_in[6];
    const float* b_hh       = (const float*)d_in[7];
    const float* fc1_w      = (const float*)d_in[8];
    const float* fc1_b      = (const float*)d_in[9];
    const float* fc2_w      = (const float*)d_in[10];
    const float* fc2_b      = (const float*)d_in[11];
    float* out = (float*)d_out;
    float* ws  = (float*)d_ws;

    float* sums  = ws;           // 428
    float* P     = ws + 512;     // 100*512
    float* hid   = ws + 51712;   // 512
    float* gpart = ws + 52224;   // 256*304
    float* cpart = ws + 130048;  // 256*128

    inproj_kernel<<<400, 128, 0, stream>>>(char_embed, W_ih, b_ih, b_hh, P);
    glove_sum_kernel<<<NBLK, 256, 0, stream>>>(word_idx, glove, gpart);
    lstm_kernel<<<NBLK, 512, 0, stream>>>(char_idx, W_hh, P, cpart);
    reduce_kernel<<<1, 512, 0, stream>>>(gpart, cpart, sums);
    fc1_kernel<<<32, 512, 0, stream>>>(fc1_w, fc1_b, sums, hid);
    fc2_kernel<<<1, 128, 0, stream>>>(fc2_w, fc2_b, hid, out);
}

// Round 7
// 605.677 us; speedup vs baseline: 1.5375x; 1.0177x over previous
//
#include <hip/hip_runtime.h>
#include <hip/hip_bf16.h>
#include <math.h>

// Problem constants
#define NW        4096   // words
#define WLEN      16     // chars per word
#define CEMB      50
#define CHID      128
#define NGATE     512    // 4*CHID
#define GDIM      300
#define FEAT      428    // GDIM + CHID
#define NHID      512
#define CVOCAB    100
#define NBLK      256    // word-blocks (glove/lstm)

// ws layout (floats) — every region fully written each launch:
//   [512, 512+51200)              P table = char_embed @ W_ih.T + b_ih + b_hh
//   [51712, 52224)                relu(fc1) hidden (512)
//   [52224, 52224+256*304)        gpart: per-block glove partials [b][304]
//   [130048, 130048+256*128)      cpart: per-block char-h partials [b][128]

typedef __attribute__((ext_vector_type(8))) short bf16x8;
typedef __attribute__((ext_vector_type(4))) float f32x4;

__device__ __forceinline__ unsigned short f2bf(float x) {
    __hip_bfloat16 h = __float2bfloat16(x);   // RNE
    return __builtin_bit_cast(unsigned short, h);
}
__device__ __forceinline__ float bf2f(unsigned short u) {
    unsigned int v = ((unsigned int)u) << 16;
    return __builtin_bit_cast(float, v);
}
__device__ __forceinline__ float sigmoid_f(float x) { return 1.f / (1.f + expf(-x)); }

// ------------------------------------------- fused inproj + glove partials
// grid 456 x 256: blocks [0,200) inproj (c = bid>>1, g = (bid&1)*256 + t);
//                 blocks [200,456) glove partials for word-block bid-200.
__global__ void fused_embed_kernel(const int* __restrict__ word_idx,
                                   const float* __restrict__ glove,
                                   const float* __restrict__ char_embed, // [100][50]
                                   const float* __restrict__ W_ih,       // [512][50]
                                   const float* __restrict__ b_ih,
                                   const float* __restrict__ b_hh,
                                   float* __restrict__ P,                // [100][512]
                                   float* __restrict__ gpart) {          // [256][304]
    const int bid = blockIdx.x, t = threadIdx.x;
    if (bid < 200) {
        __shared__ float ce[CEMB];
        const int c = bid >> 1;
        const int g = (bid & 1) * 256 + t;
        if (t < CEMB) ce[t] = char_embed[c * CEMB + t];
        __syncthreads();
        float acc = b_ih[g] + b_hh[g];
        const float* wrow = W_ih + g * CEMB;  // 102 KB table, L2-resident
#pragma unroll
        for (int e = 0; e < CEMB; ++e) acc = fmaf(ce[e], wrow[e], acc);
        P[c * NGATE + g] = acc;
    } else {
        const int b = bid - 200;
        const int wbase = b * 16;
        float acc0 = 0.f, acc1 = 0.f;
#pragma unroll
        for (int w = 0; w < 16; ++w) {
            const int row = word_idx[wbase + w];
            const float* r = glove + (size_t)row * GDIM;
            if (t < GDIM) acc0 += r[t];
            if (t + 256 < GDIM) acc1 += r[t + 256];
        }
        if (t < GDIM) gpart[b * 304 + t] = acc0;
        if (t + 256 < GDIM) gpart[b * 304 + t + 256] = acc1;
    }
}

// ----------------------------------------------------------------- the LSTM
// 256 blocks x 512 threads (8 waves); block owns 16 words, 16 steps.
// Split-precision MFMA: Whh = Ahi + Alo (bf16 pair), H = Bhi + Blo (bf16 pair).
// G = Ahi*Bhi + Alo*Bhi + Ahi*Blo  (fp32 accum; dropped term ~2^-18 relative).
// Wave wm owns m-tiles {wm, wm+8, wm+16, wm+24} = i/f/g/o gates of cells
// [wm*16, wm*16+16) -> all four gates of a cell land in the same thread.
// H is double-buffered -> single barrier per step (WAR covered by alternation).
// Per-block h-sums go to cpart[b][128] (no atomics -> bit-deterministic).
__global__ __launch_bounds__(512, 2)
void lstm_kernel(const int* __restrict__ char_idx,  // [4096][16]
                 const float* __restrict__ Whh,     // [512][128]
                 const float* __restrict__ P,       // [100][512]
                 float* __restrict__ cpart) {       // [256][128]
    __shared__ __align__(16) unsigned short Hh[2][16 * 128];  // hi, swizzled, 2x4KB
    __shared__ __align__(16) unsigned short Hl[2][16 * 128];  // lo, swizzled, 2x4KB
    __shared__ int ci[16][17];                                // [word][step], padded
    const int t = threadIdx.x;
    const int wm = t >> 6, lane = t & 63;
    const int w = lane & 15, hi = lane >> 4;

    // ---- A fragments: Whh split hi/lo bf16. m = lane&15; k = ks*32 + hi*8 + j
    // (A and B use the same positional lane->k map, so contraction is exact).
    bf16x8 ah[4][4], al[4][4];
#pragma unroll
    for (int r = 0; r < 4; ++r) {
        const int g = (wm + 8 * r) * 16 + (lane & 15);
        const float* wp = Whh + g * CHID + hi * 8;
#pragma unroll
        for (int ks = 0; ks < 4; ++ks) {
            union { bf16x8 v; unsigned short u[8]; } ph, pl;
#pragma unroll
            for (int j = 0; j < 8; ++j) {
                const float x = wp[ks * 32 + j];
                const unsigned short xh = f2bf(x);
                ph.u[j] = xh;
                pl.u[j] = f2bf(x - bf2f(xh));
            }
            ah[r][ks] = ph.v;
            al[r][ks] = pl.v;
        }
    }

    // ---- char indices for this block's 16 words
    const int wbase = blockIdx.x * 16;
    if (t < 256) ci[t >> 4][t & 15] = char_idx[(wbase + (t >> 4)) * WLEN + (t & 15)];

    // ---- zero H buffer 0 (bf16 zero == 0 bits)
    {
        unsigned int* hz = (unsigned int*)&Hh[0][0];
        hz[t] = 0u; hz[t + 512] = 0u;
        unsigned int* lz = (unsigned int*)&Hl[0][0];
        lz[t] = 0u; lz[t + 512] = 0u;
    }

    float cst[4] = {0.f, 0.f, 0.f, 0.f};
    float hreg[4] = {0.f, 0.f, 0.f, 0.f};
    __syncthreads();

    for (int s = 0; s < WLEN; ++s) {
        const int cur = s & 1, nxt = cur ^ 1;

        // P gather for this step (issued early; consumed after MFMAs)
        const int cix = ci[w][s];
        const float* prow = P + cix * NGATE + wm * 16 + hi * 4;
        f32x4 pv[4];
#pragma unroll
        for (int r = 0; r < 4; ++r) pv[r] = *(const f32x4*)(prow + r * 128);

        // B fragments from swizzled LDS: b[ks][j] = H[ks*32+hi*8+j][w]
        bf16x8 bh[4], bl[4];
#pragma unroll
        for (int ks = 0; ks < 4; ++ks) {
            const int chunk = (ks * 4 + hi) ^ w;  // 16B-chunk XOR swizzle
            bh[ks] = *(const bf16x8*)((const char*)&Hh[cur][0] + w * 256 + chunk * 16);
            bl[ks] = *(const bf16x8*)((const char*)&Hl[cur][0] + w * 256 + chunk * 16);
        }

        // MFMA: d[r] = Ahi*Bhi + Alo*Bhi + Ahi*Blo (fp32 accum from zero)
        f32x4 d[4];
#pragma unroll
        for (int r = 0; r < 4; ++r) d[r] = (f32x4){0.f, 0.f, 0.f, 0.f};
#pragma unroll
        for (int ks = 0; ks < 4; ++ks)
#pragma unroll
            for (int r = 0; r < 4; ++r)
                d[r] = __builtin_amdgcn_mfma_f32_16x16x32_bf16(ah[r][ks], bh[ks], d[r], 0, 0, 0);
#pragma unroll
        for (int ks = 0; ks < 4; ++ks)
#pragma unroll
            for (int r = 0; r < 4; ++r)
                d[r] = __builtin_amdgcn_mfma_f32_16x16x32_bf16(al[r][ks], bh[ks], d[r], 0, 0, 0);
#pragma unroll
        for (int ks = 0; ks < 4; ++ks)
#pragma unroll
            for (int r = 0; r < 4; ++r)
                d[r] = __builtin_amdgcn_mfma_f32_16x16x32_bf16(ah[r][ks], bl[ks], d[r], 0, 0, 0);

        // Cell update: thread owns cells n = wm*16 + hi*4 + reg, word w.
        // D layout (verified m89): col = lane&15 (= word), row = hi*4 + reg.
        // Write next-step H into the OTHER buffer (no WAR with this step's reads).
#pragma unroll
        for (int reg = 0; reg < 4; ++reg) {
            const float ig = d[0][reg] + pv[0][reg];
            const float fg = d[1][reg] + pv[1][reg];
            const float gg = d[2][reg] + pv[2][reg];
            const float og = d[3][reg] + pv[3][reg];
            const float si = sigmoid_f(ig);
            const float sf = sigmoid_f(fg);
            const float so = sigmoid_f(og);
            cst[reg] = sf * cst[reg] + si * tanhf(gg);   // libm tanh: no cancellation
            const float hv = so * tanhf(cst[reg]);
            hreg[reg] = hv;
            const int n = wm * 16 + hi * 4 + reg;
            const int idx = w * 128 + (((n >> 3) ^ w) << 3) + (n & 7);
            const unsigned short hh16 = f2bf(hv);
            Hh[nxt][idx] = hh16;
            Hl[nxt][idx] = f2bf(hv - bf2f(hh16));
        }
        __syncthreads();  // writes to buf[nxt] visible before next step reads it
    }

    // ---- reduce h over this block's 16 words (xor within 16-lane group),
    //      store per-block partial (deterministic, no atomics)
#pragma unroll
    for (int reg = 0; reg < 4; ++reg) {
        float v = hreg[reg];
#pragma unroll
        for (int m = 1; m < 16; m <<= 1) v += __shfl_xor(v, m);
        if ((lane & 15) == 0)
            cpart[blockIdx.x * CHID + wm * 16 + hi * 4 + reg] = v;
    }
}

// ---------------------------------------- fused tail: reduce + fc1 (relu)
// 32 blocks x 512 threads. Each block redoes the deterministic partial
// reduction (identical serial order -> bit-identical avg in every block),
// then computes its 16 fc1 rows (32 lanes per row).
__global__ void tail_kernel(const float* __restrict__ gpart, // [256][304]
                            const float* __restrict__ cpart, // [256][128]
                            const float* __restrict__ fc1_w, // [512][428]
                            const float* __restrict__ fc1_b,
                            float* __restrict__ hid) {
    __shared__ __align__(16) float avg[FEAT];
    const int t = threadIdx.x;
    if (t < FEAT) {
        float a0 = 0.f, a1 = 0.f, a2 = 0.f, a3 = 0.f;
        if (t < GDIM) {
            for (int b = 0; b < NBLK; b += 4) {
                a0 += gpart[(b + 0) * 304 + t];
                a1 += gpart[(b + 1) * 304 + t];
                a2 += gpart[(b + 2) * 304 + t];
                a3 += gpart[(b + 3) * 304 + t];
            }
        } else {
            const int n = t - GDIM;
            for (int b = 0; b < NBLK; b += 4) {
                a0 += cpart[(b + 0) * CHID + n];
                a1 += cpart[(b + 1) * CHID + n];
                a2 += cpart[(b + 2) * CHID + n];
                a3 += cpart[(b + 3) * CHID + n];
            }
        }
        avg[t] = ((a0 + a1) + (a2 + a3)) * (1.f / (float)NW);
    }
    __syncthreads();

    const int wave = t >> 6, lane = t & 63;
    const int half = lane >> 5, lane32 = lane & 31;
    const int r = blockIdx.x * 16 + wave * 2 + half;

    float acc = 0.f;
    const float* row = fc1_w + (size_t)r * FEAT;
#pragma unroll
    for (int i = 0; i < 4; ++i) {
        const int c0 = i * 128 + lane32 * 4;
        if (c0 + 4 <= FEAT) {
            const f32x4 wv = *(const f32x4*)(row + c0);
            const f32x4 av = *(const f32x4*)(avg + c0);
            acc = fmaf(av[0], wv[0], acc);
            acc = fmaf(av[1], wv[1], acc);
            acc = fmaf(av[2], wv[2], acc);
            acc = fmaf(av[3], wv[3], acc);
        }
    }
#pragma unroll
    for (int m = 1; m < 32; m <<= 1) acc += __shfl_xor(acc, m);
    if (lane32 == 0) hid[r] = fmaxf(acc + fc1_b[r], 0.f);
}

// ---------------------------------------------------------------- fc2
__global__ void fc2_kernel(const float* __restrict__ fc2_w, // [2][512]
                           const float* __restrict__ fc2_b,
                           const float* __restrict__ hid,
                           float* __restrict__ out) {
    const int t = threadIdx.x;  // 128
    const int r = t >> 6, lane = t & 63;
    float p = 0.f;
#pragma unroll
    for (int i = 0; i < 8; ++i)
        p = fmaf(hid[i * 64 + lane], fc2_w[r * NHID + i * 64 + lane], p);
#pragma unroll
    for (int off = 32; off > 0; off >>= 1) p += __shfl_down(p, off);
    if (lane == 0) out[r] = p + fc2_b[r];
}

// ---------------------------------------------------------------- launcher
extern "C" void kernel_launch(void* const* d_in, const int* in_sizes, int n_in,
                              void* d_out, int out_size, void* d_ws, size_t ws_size,
                              hipStream_t stream) {
    const int*   word_idx   = (const int*)d_in[0];
    const int*   char_idx   = (const int*)d_in[1];
    const float* glove      = (const float*)d_in[2];
    const float* char_embed = (const float*)d_in[3];
    const float* W_ih       = (const float*)d_in[4];
    const float* W_hh       = (const float*)d_in[5];
    const float* b_ih       = (const float*)d_in[6];
    const float* b_hh       = (const float*)d_in[7];
    const float* fc1_w      = (const float*)d_in[8];
    const float* fc1_b      = (const float*)d_in[9];
    const float* fc2_w      = (const float*)d_in[10];
    const float* fc2_b      = (const float*)d_in[11];
    float* out = (float*)d_out;
    float* ws  = (float*)d_ws;

    float* P     = ws + 512;     // 100*512
    float* hid   = ws + 51712;   // 512
    float* gpart = ws + 52224;   // 256*304
    float* cpart = ws + 130048;  // 256*128

    fused_embed_kernel<<<456, 256, 0, stream>>>(word_idx, glove, char_embed,
                                                W_ih, b_ih, b_hh, P, gpart);
    lstm_kernel<<<NBLK, 512, 0, stream>>>(char_idx, W_hh, P, cpart);
    tail_kernel<<<32, 512, 0, stream>>>(gpart, cpart, fc1_w, fc1_b, hid);
    fc2_kernel<<<1, 128, 0, stream>>>(fc2_w, fc2_b, hid, out);
}